// Round 8
// baseline (591.524 us; speedup 1.0000x reference)
//
#include <hip/hip_runtime.h>
#include <hip/hip_bf16.h>

// HieraMaskUnitAttention on MI355X (gfx950).
// B=8 T=8192 D=768 H=12 HD=64 Q_STRIDE=4 WINDOW=64 -> nw=32, seq=256, q_len=64
//
// Pipeline (R8):
//   1) cvt_bf16: qkv_w / proj_w fp32 -> bf16 (embeddings cvt FUSED into GEMM)
//   2) gemm256f<bf16 out>: qkv = emb(fp32) @ qkv_w^T + qkv_b  [65536 x 2304] bf16
//      NON-PERSISTENT 2304 blocks, XCD-swizzled N-fast (R2 grid: A-panels shared
//      via same-XCD L2 -> A fp32 read ~once). A reg-staged with v_cvt_pk_bf16_f32;
//      B via global_load_lds. Ordering: A-loads' in-order vmcnt retire drains all
//      older B-DMAs (R6-proven); lgkmcnt(0) hardening before BAR in A-phases.
//   3) attn_kernel (R7): Q max-pool, QK^T softmax (attn fp32 -> d_out), PV -> X ws
//   4) gemm_bt<f32 out>: out = X @ proj_w^T + proj_b (XOR-swizzled LDS)

typedef float  f32x4  __attribute__((ext_vector_type(4)));
typedef __bf16 bf16x8 __attribute__((ext_vector_type(8)));

__device__ __forceinline__ unsigned short f2bf(float f) {
  unsigned int u = __float_as_uint(f);
  u += 0x7fffu + ((u >> 16) & 1u);      // RNE
  return (unsigned short)(u >> 16);
}
__device__ __forceinline__ float bf2f(unsigned short b) {
  return __uint_as_float(((unsigned int)b) << 16);
}

#define GLOAD_LDS16(gptr, lptr) __builtin_amdgcn_global_load_lds( \
    (const __attribute__((address_space(1))) void*)(gptr),        \
    (__attribute__((address_space(3))) void*)(lptr), 16, 0, 0)

// ---------------------------------------------------------------- cvt fp32->bf16
__global__ void cvt_bf16(const float* __restrict__ src,
                         unsigned short* __restrict__ dst, int n4) {
  int i = blockIdx.x * blockDim.x + threadIdx.x;
  const int stride = gridDim.x * blockDim.x;
  for (; i < n4; i += stride) {
    const float4 v = ((const float4*)src)[i];
    ushort4 o;
    o.x = f2bf(v.x); o.y = f2bf(v.y); o.z = f2bf(v.z); o.w = f2bf(v.w);
    ((ushort4*)dst)[i] = o;
  }
}

// ---------------------------------------------------------------- fused 256x256 GEMM
// C = A(fp32) @ B(bf16)^T + bias. A: [M x K] f32 K-fast, B: [N x K] bf16 K-fast.
// Grid = (M/256)*(N/256) blocks, XCD-bijective swizzle, N-fast ordering (the 9
// blocks sharing an A-row-panel are wg-consecutive -> same XCD L2).
// LDS regions: A(par,kh)=par*32768+kh*16384, B=+65536; par = t&1.
// Per K-tile t (4 phases):
//   ph1 stage-A(t+1,kh1) [4xfloat4 -> cvt_pk -> 2x ds_write_b128] + lgkm0
//   ph2 stage-B(t+1,kh1) [2x global_load_lds]
//   ph3 stage-A(t+2,kh0) + lgkm0
//   ph4 stage-B(t+2,kh0)
// Ordering (R6-proven): every B-stage is followed <=2 phases later by an A-stage
// whose cvt waits (in-order vmcnt) drain it, >=1 barrier before its readers;
// A ds_writes drained by explicit lgkmcnt(0) before the phase barrier; WAR
// restage targets >=2 barriers dead.
// Swizzle: byte p ^= ((p>>7)&3)<<4 via swizzled source csel, applied on reads.
template <int OUT_BF16>
__global__ __launch_bounds__(512, 2) void gemm256f(
    const float* __restrict__ A, const unsigned short* __restrict__ B,
    const float* __restrict__ bias, void* __restrict__ Cout,
    int M, int N, int K) {
  extern __shared__ char lds[];

  const int tid  = threadIdx.x;
  const int lane = tid & 63;
  const int wid  = tid >> 6;
  const int g16  = (lane >> 4) & 3;
  const int l15  = lane & 15;
  const int wm   = wid >> 2;      // 0..1
  const int wn   = wid & 3;       // 0..3

  // XCD-bijective block swizzle (grid % 8 == 0), N-tile-fast ordering.
  const int nbn = N >> 8;
  const int wg  = (blockIdx.x & 7) * ((int)gridDim.x >> 3) + (blockIdx.x >> 3);
  const size_t bm = (size_t)(wg / nbn) << 8;
  const size_t bn = (size_t)(wg % nbn) << 8;

  const int NT = K >> 6;          // 12

  // ---- staging precompute (swizzled source element, linear LDS dest) ----
  const int srow = tid >> 2;                                   // 0..127
  const int csel = (((tid & 3) ^ ((tid >> 3) & 3)) << 3);      // element offset
  const int dstb = tid * 16;                                   // per-lane dest
  const int ldst = wid * 1024;                                 // wave-uniform base
  const float* pA0f = A + (bm + srow) * (size_t)K + csel;
  const float* pA1f = pA0f + (size_t)128 * K;
  const unsigned short* pB0 = B + (bn + srow) * (size_t)K + csel;
  const unsigned short* pB1 = pB0 + (size_t)128 * K;

#define STAGE_A(koff, regbase)                                           \
  do {                                                                   \
    const float4 x0 = *(const float4*)(pA0f + (koff));                   \
    const float4 x1 = *(const float4*)(pA0f + (koff) + 4);               \
    const float4 x2 = *(const float4*)(pA1f + (koff));                   \
    const float4 x3 = *(const float4*)(pA1f + (koff) + 4);               \
    int4 q0, q1;                                                         \
    asm("v_cvt_pk_bf16_f32 %0, %1, %2" : "=v"(q0.x) : "v"(x0.x), "v"(x0.y)); \
    asm("v_cvt_pk_bf16_f32 %0, %1, %2" : "=v"(q0.y) : "v"(x0.z), "v"(x0.w)); \
    asm("v_cvt_pk_bf16_f32 %0, %1, %2" : "=v"(q0.z) : "v"(x1.x), "v"(x1.y)); \
    asm("v_cvt_pk_bf16_f32 %0, %1, %2" : "=v"(q0.w) : "v"(x1.z), "v"(x1.w)); \
    asm("v_cvt_pk_bf16_f32 %0, %1, %2" : "=v"(q1.x) : "v"(x2.x), "v"(x2.y)); \
    asm("v_cvt_pk_bf16_f32 %0, %1, %2" : "=v"(q1.y) : "v"(x2.z), "v"(x2.w)); \
    asm("v_cvt_pk_bf16_f32 %0, %1, %2" : "=v"(q1.z) : "v"(x3.x), "v"(x3.y)); \
    asm("v_cvt_pk_bf16_f32 %0, %1, %2" : "=v"(q1.w) : "v"(x3.z), "v"(x3.w)); \
    *(int4*)(lds + (regbase) + dstb)        = q0;                        \
    *(int4*)(lds + (regbase) + 8192 + dstb) = q1;                        \
  } while (0)
#define STAGE_B(boff, regbase)                                          \
  do {                                                                  \
    GLOAD_LDS16(pB0 + (boff), lds + (regbase) + ldst);                  \
    GLOAD_LDS16(pB1 + (boff), lds + (regbase) + 8192 + ldst);           \
  } while (0)

  // ---- fragment-read precompute (2 lanes/bank -> conflict-free) ----
  const int s16  = ((g16 ^ ((l15 >> 1) & 3)) << 4);
  const int offA = (wm * 128 + l15) * 64 + s16;   // + rh*4096 + q*1024
  const int offB = (wn * 64 + l15) * 64 + s16;    // + c*1024

  f32x4 acc[8][4];
  const f32x4 zero4 = {0.f, 0.f, 0.f, 0.f};
#pragma unroll
  for (int i = 0; i < 8; ++i)
#pragma unroll
    for (int j = 0; j < 4; ++j) acc[i][j] = zero4;

#define READ_A(par, kk, rh)                                              \
  { const char* rb = lds + (par) * 32768 + (kk) * 16384 + offA + (rh) * 4096; \
    af[0] = *(const bf16x8*)(rb);                                        \
    af[1] = *(const bf16x8*)(rb + 1024);                                 \
    af[2] = *(const bf16x8*)(rb + 2048);                                 \
    af[3] = *(const bf16x8*)(rb + 3072); }
#define READ_B(par, kk)                                                  \
  { const char* rb = lds + 65536 + (par) * 32768 + (kk) * 16384 + offB;  \
    bfv[0] = *(const bf16x8*)(rb);                                       \
    bfv[1] = *(const bf16x8*)(rb + 1024);                                \
    bfv[2] = *(const bf16x8*)(rb + 2048);                                \
    bfv[3] = *(const bf16x8*)(rb + 3072); }
#define MFMA16(rh)                                                       \
  _Pragma("unroll") for (int q = 0; q < 4; ++q)                          \
  _Pragma("unroll") for (int c = 0; c < 4; ++c)                          \
    acc[(rh) * 4 + q][c] = __builtin_amdgcn_mfma_f32_16x16x32_bf16(      \
        af[q], bfv[c], acc[(rh) * 4 + q][c], 0, 0, 0);
#define BAR() __builtin_amdgcn_s_barrier()
#define LGKM0() asm volatile("s_waitcnt lgkmcnt(0)" ::: "memory")

  // ---- prologue: step 0 both halves + step 1 Kh0 ----
  STAGE_A(0, 0);
  STAGE_B(0, 65536);
  STAGE_A(32, 16384);                 // cvt waits drain B(0,kh0)
  STAGE_B(32, 65536 + 16384);
  STAGE_A(64, 32768);                 // cvt waits drain B(0,kh1)
  STAGE_B(64, 65536 + 32768);
  LGKM0();
  BAR();

  for (int t = 0; t < NT; ++t) {
    const int par  = t & 1;
    const int parn = par ^ 1;
    const int kc1  = (t + 1 < NT ? t + 1 : NT - 1) * 64;
    const int kc2  = (t + 2 < NT ? t + 2 : NT - 1) * 64;
    bf16x8 af[4], bfv[4];

    // ph1: frags (par,kh0,rh0) | stage A->(parn,kh1) [t+1]
    READ_A(par, 0, 0); READ_B(par, 0);
    STAGE_A(kc1 + 32, parn * 32768 + 16384);
    LGKM0();
    BAR();
    __builtin_amdgcn_s_setprio(1); MFMA16(0); __builtin_amdgcn_s_setprio(0);
    BAR();

    // ph2: frags (par,kh0,rh1) | stage B->(parn,kh1)
    READ_A(par, 0, 1);
    STAGE_B(kc1 + 32, 65536 + parn * 32768 + 16384);
    BAR();
    __builtin_amdgcn_s_setprio(1); MFMA16(1); __builtin_amdgcn_s_setprio(0);
    BAR();

    // ph3: frags (par,kh1,rh0) | stage A->(par,kh0) [t+2]
    READ_A(par, 1, 0); READ_B(par, 1);
    STAGE_A(kc2, par * 32768);
    LGKM0();
    BAR();
    __builtin_amdgcn_s_setprio(1); MFMA16(0); __builtin_amdgcn_s_setprio(0);
    BAR();

    // ph4: frags (par,kh1,rh1) | stage B->(par,kh0)
    READ_A(par, 1, 1);
    STAGE_B(kc2, 65536 + par * 32768);
    BAR();
    __builtin_amdgcn_s_setprio(1); MFMA16(1); __builtin_amdgcn_s_setprio(0);
    BAR();
  }

  // ---- epilogue: + bias, store ----
#pragma unroll
  for (int ai = 0; ai < 8; ++ai) {
    const size_t row0 = bm + wm * 128 + (ai >> 2) * 64 + (ai & 3) * 16 + g16 * 4;
#pragma unroll
    for (int c = 0; c < 4; ++c) {
      const size_t col = bn + wn * 64 + c * 16 + l15;
      const float bv = bias[col];
#pragma unroll
      for (int r = 0; r < 4; ++r) {
        const float v = acc[ai][c][r] + bv;
        const size_t idx = (row0 + r) * N + col;
        if (OUT_BF16) ((unsigned short*)Cout)[idx] = f2bf(v);
        else          ((float*)Cout)[idx] = v;
      }
    }
  }
#undef STAGE_A
#undef STAGE_B
#undef READ_A
#undef READ_B
#undef MFMA16
#undef BAR
#undef LGKM0
}

// ---------------------------------------------------------------- GEMM C = A @ B^T + bias
// 128x128 2-phase kernel for the proj GEMM. XOR bank swizzle
// (slot ^= row&3 within each 128B row) on staging source + fragment reads.
template <int OUT_BF16>
__global__ __launch_bounds__(256) void gemm_bt(
    const unsigned short* __restrict__ A, const unsigned short* __restrict__ B,
    const float* __restrict__ bias, void* __restrict__ Cout,
    int M, int N, int K) {
  __shared__ unsigned short As[128 * 64];
  __shared__ unsigned short Bs[128 * 64];

  const int tid  = threadIdx.x;
  const int lane = tid & 63;
  const int wid  = tid >> 6;
  const int g16  = lane >> 4;     // 0..3
  const int l15  = lane & 15;
  const int bm = blockIdx.x * 128;
  const int bn = blockIdx.y * 128;
  const int wr = (wid >> 1) * 64;
  const int wc = (wid & 1) * 64;

  const f32x4 zero4 = {0.f, 0.f, 0.f, 0.f};
  f32x4 acc[4][4];
#pragma unroll
  for (int m = 0; m < 4; ++m)
#pragma unroll
    for (int n = 0; n < 4; ++n) acc[m][n] = zero4;

  const int flatBase = tid * 16;  // byte offset within 16KB tile
  const int rsw = l15 & 3;        // read-side row&3

  for (int kt = 0; kt < K; kt += 64) {
#pragma unroll
    for (int c = 0; c < 4; ++c) {
      const int flat = c * 4096 + flatBase;
      const int row  = flat >> 7;                     // 128 B per tile row
      const int slot = (flat >> 4) & 7;
      const int cole = (((slot) ^ (row & 3)) << 3);   // swizzled source elems
      const unsigned short* ga = A + (size_t)(bm + row) * K + kt + cole;
      const unsigned short* gb = B + (size_t)(bn + row) * K + kt + cole;
      GLOAD_LDS16(ga, (char*)As + c * 4096 + wid * 1024 + lane * 16);
      GLOAD_LDS16(gb, (char*)Bs + c * 4096 + wid * 1024 + lane * 16);
    }
    __syncthreads();
#pragma unroll
    for (int kk = 0; kk < 2; ++kk) {
      bf16x8 af[4], bfv[4];
#pragma unroll
      for (int m = 0; m < 4; ++m)
        af[m] = *(const bf16x8*)((const char*)As +
                 (wr + m * 16 + l15) * 128 + (((kk * 4 + g16) ^ rsw) << 4));
#pragma unroll
      for (int n = 0; n < 4; ++n)
        bfv[n] = *(const bf16x8*)((const char*)Bs +
                 (wc + n * 16 + l15) * 128 + (((kk * 4 + g16) ^ rsw) << 4));
#pragma unroll
      for (int m = 0; m < 4; ++m)
#pragma unroll
        for (int n = 0; n < 4; ++n)
          acc[m][n] = __builtin_amdgcn_mfma_f32_16x16x32_bf16(af[m], bfv[n],
                                                              acc[m][n], 0, 0, 0);
    }
    __syncthreads();
  }

#pragma unroll
  for (int n = 0; n < 4; ++n) {
    const int col = bn + wc + n * 16 + l15;
    const float bv = bias[col];
#pragma unroll
    for (int m = 0; m < 4; ++m) {
      const int rowb = bm + wr + m * 16 + g16 * 4;
#pragma unroll
      for (int r = 0; r < 4; ++r) {
        const float v = acc[m][n][r] + bv;
        const size_t idx = (size_t)(rowb + r) * N + col;
        if (OUT_BF16) ((unsigned short*)Cout)[idx] = f2bf(v);
        else          ((float*)Cout)[idx] = v;
      }
    }
  }
}

// ---------------------------------------------------------------- fused mask-unit attention
// One block (256 thr, 4 waves) per (b,h,w). Wave handles 16 q-rows.
// LDS 64KB: K [256x64] swizzled (reused as per-wave P after barrier), Vt [64x256] swizzled.
// V staged via register 4x8 transpose + ds_write_b64 (R7).
__global__ __launch_bounds__(256) void attn_kernel(
    const unsigned short* __restrict__ qkv,   // [65536 x 2304] bf16
    float* __restrict__ attn_out,             // [b,h,w,64,256] fp32
    unsigned short* __restrict__ Xws) {       // [16384 x 768] bf16
  __shared__ unsigned short smem[32768];
  char* KP = (char*)smem;             // 32KB K region / later P region
  char* VT = (char*)(smem + 16384);   // 32KB V transposed [d][s]

  const int tid  = threadIdx.x;
  const int lane = tid & 63;
  const int wid  = tid >> 6;
  const int g16  = lane >> 4;
  const int l15  = lane & 15;

  const int bid = blockIdx.x;         // ((b*12 + h)*32 + w)
  const int w = bid & 31;
  const int h = (bid >> 5) % 12;
  const int b = bid / 384;

  const int s0 = tid >> 3;            // 0..31
  const int part = tid & 7;

  // ---- stage K (swizzled rows, b128 writes) ----
#pragma unroll
  for (int p = 0; p < 8; ++p) {
    const int s = s0 + p * 32;
    const size_t gbase =
        ((size_t)b * 8192 + (size_t)s * 32 + w) * 2304 + h * 64 + part * 8;
    int4 kv = *(const int4*)(qkv + gbase + 768);
    *(int4*)(KP + ((s * 128 + part * 16) ^ ((s & 7) << 4))) = kv;
  }

  // ---- stage V transposed: 4 consecutive s per thread, packed b64 writes ----
#pragma unroll
  for (int p = 0; p < 2; ++p) {
    const int s = s0 * 4 + p * 128;   // 4-aligned
    const size_t gb0 =
        ((size_t)b * 8192 + (size_t)s * 32 + w) * 2304 + 1536 + h * 64 + part * 8;
    int4 x0 = *(const int4*)(qkv + gb0);
    int4 x1 = *(const int4*)(qkv + gb0 + 73728);    // +32*2304 (s+1)
    int4 x2 = *(const int4*)(qkv + gb0 + 147456);   // s+2
    int4 x3 = *(const int4*)(qkv + gb0 + 221184);   // s+3
    const unsigned int* u0 = (const unsigned int*)&x0;
    const unsigned int* u1 = (const unsigned int*)&x1;
    const unsigned int* u2 = (const unsigned int*)&x2;
    const unsigned int* u3 = (const unsigned int*)&x3;
#pragma unroll
    for (int k = 0; k < 4; ++k) {
      const unsigned int lo01 = (u0[k] & 0xffffu) | (u1[k] << 16);
      const unsigned int lo23 = (u2[k] & 0xffffu) | (u3[k] << 16);
      const unsigned int hi01 = (u0[k] >> 16) | (u1[k] & 0xffff0000u);
      const unsigned int hi23 = (u2[k] >> 16) | (u3[k] & 0xffff0000u);
      const int dlo = part * 8 + 2 * k;
      const int dhi = dlo + 1;
      uint2 vlo; vlo.x = lo01; vlo.y = lo23;   // V[s..s+3][dlo]
      uint2 vhi; vhi.x = hi01; vhi.y = hi23;   // V[s..s+3][dhi]
      *(uint2*)(VT + ((dlo * 512 + s * 2) ^ ((dlo & 7) << 4))) = vlo;
      *(uint2*)(VT + ((dhi * 512 + s * 2) ^ ((dhi & 7) << 4))) = vhi;
    }
  }

  // ---- gather Q with interleaved max-pool directly into A-fragments ----
  union BU { unsigned short u[8]; bf16x8 v; };
  BU aq0, aq1;
  {
    const int qrow = wid * 16 + l15;
    float q0[8], q1[8];
#pragma unroll
    for (int j = 0; j < 8; ++j) { q0[j] = -1e30f; q1[j] = -1e30f; }
#pragma unroll
    for (int g = 0; g < 4; ++g) {
      const size_t gbase =
          ((size_t)b * 8192 + (size_t)(g * 64 + qrow) * 32 + w) * 2304 +
          h * 64 + g16 * 8;
      int4 a = *(const int4*)(qkv + gbase);
      int4 c = *(const int4*)(qkv + gbase + 32);
      const unsigned short* pa = (const unsigned short*)&a;
      const unsigned short* pc = (const unsigned short*)&c;
#pragma unroll
      for (int j = 0; j < 8; ++j) {
        q0[j] = fmaxf(q0[j], bf2f(pa[j]));
        q1[j] = fmaxf(q1[j], bf2f(pc[j]));
      }
    }
#pragma unroll
    for (int j = 0; j < 8; ++j) {   // values are exact bf16 -> truncation exact
      aq0.u[j] = (unsigned short)(__float_as_uint(q0[j]) >> 16);
      aq1.u[j] = (unsigned short)(__float_as_uint(q1[j]) >> 16);
    }
  }

  __syncthreads();

  // ---- S = Q K^T (16 col-tiles of 16), scale ----
  f32x4 sacc[16];
  const f32x4 zero4 = {0.f, 0.f, 0.f, 0.f};
#pragma unroll
  for (int t = 0; t < 16; ++t) sacc[t] = zero4;
#pragma unroll
  for (int t = 0; t < 16; ++t) {
    const int srow = t * 16 + l15;
    bf16x8 bk0 = *(const bf16x8*)(KP + ((srow * 128 + 0  + g16 * 16) ^ ((srow & 7) << 4)));
    bf16x8 bk1 = *(const bf16x8*)(KP + ((srow * 128 + 64 + g16 * 16) ^ ((srow & 7) << 4)));
    sacc[t] = __builtin_amdgcn_mfma_f32_16x16x32_bf16(aq0.v, bk0, sacc[t], 0, 0, 0);
    sacc[t] = __builtin_amdgcn_mfma_f32_16x16x32_bf16(aq1.v, bk1, sacc[t], 0, 0, 0);
  }

  // ---- softmax over 256 (16-lane-group shuffle reduce per row) ----
  float inv_[4];
#pragma unroll
  for (int r = 0; r < 4; ++r) {
    float m = -1e30f;
#pragma unroll
    for (int t = 0; t < 16; ++t) { sacc[t][r] *= 0.125f; m = fmaxf(m, sacc[t][r]); }
#pragma unroll
    for (int off = 1; off < 16; off <<= 1) m = fmaxf(m, __shfl_xor(m, off, 64));
    float ssum = 0.f;
#pragma unroll
    for (int t = 0; t < 16; ++t) {
      float e = expf(sacc[t][r] - m);
      sacc[t][r] = e;
      ssum += e;
    }
#pragma unroll
    for (int off = 1; off < 16; off <<= 1) ssum += __shfl_xor(ssum, off, 64);
    inv_[r] = 1.f / ssum;
  }

  // ---- write attn (fp32) and keep normalized P in regs ----
  {
    float* ab = attn_out + ((size_t)bid * 64 + wid * 16) * 256;
#pragma unroll
    for (int t = 0; t < 16; ++t)
#pragma unroll
      for (int r = 0; r < 4; ++r) {
        const float p = sacc[t][r] * inv_[r];
        sacc[t][r] = p;
        ab[(size_t)(g16 * 4 + r) * 256 + t * 16 + l15] = p;
      }
  }

  __syncthreads();   // all waves finished reading K -> reuse region for P

  // ---- P (bf16) into per-wave LDS region, swizzled ----
  {
    char* PW = KP + wid * 8192;
#pragma unroll
    for (int t = 0; t < 16; ++t)
#pragma unroll
      for (int r = 0; r < 4; ++r) {
        const int row = g16 * 4 + r;
        *(unsigned short*)(PW + ((row * 512 + (t * 16 + l15) * 2) ^ ((row & 7) << 4))) =
            f2bf(sacc[t][r]);
      }
  }

  // ---- O = P V ----
  f32x4 oacc[4];
#pragma unroll
  for (int n = 0; n < 4; ++n) oacc[n] = zero4;
  {
    const char* PR = KP + wid * 8192;
#pragma unroll
    for (int kc = 0; kc < 8; ++kc) {
      bf16x8 pa = *(const bf16x8*)(PR + ((l15 * 512 + kc * 64 + g16 * 16) ^ ((l15 & 7) << 4)));
#pragma unroll
      for (int n = 0; n < 4; ++n) {
        const int d = n * 16 + l15;
        bf16x8 vv = *(const bf16x8*)(VT + ((d * 512 + kc * 64 + g16 * 16) ^ ((d & 7) << 4)));
        oacc[n] = __builtin_amdgcn_mfma_f32_16x16x32_bf16(pa, vv, oacc[n], 0, 0, 0);
      }
    }
  }

  // ---- write X for proj GEMM: row = b*2048 + qi*32 + w, col = h*64 + d ----
#pragma unroll
  for (int n = 0; n < 4; ++n)
#pragma unroll
    for (int r = 0; r < 4; ++r) {
      const int qi = wid * 16 + g16 * 4 + r;
      Xws[((size_t)b * 2048 + qi * 32 + w) * 768 + h * 64 + n * 16 + l15] =
          f2bf(oacc[n][r]);
    }
}

// ---------------------------------------------------------------- launch
extern "C" void kernel_launch(void* const* d_in, const int* in_sizes, int n_in,
                              void* d_out, int out_size, void* d_ws, size_t ws_size,
                              hipStream_t stream) {
  const float* emb    = (const float*)d_in[0];
  const float* qkv_w  = (const float*)d_in[1];
  const float* qkv_b  = (const float*)d_in[2];
  const float* proj_w = (const float*)d_in[3];
  const float* proj_b = (const float*)d_in[4];
  float* out = (float*)d_out;

  char* ws = (char*)d_ws;
  unsigned short* wqkvB  = (unsigned short*)(ws + 100663296);
  unsigned short* wprojB = (unsigned short*)(ws + 104202240);
  unsigned short* qkvB   = (unsigned short*)(ws + 105381888);
  unsigned short* Xws    = (unsigned short*)(ws + 407371776);

  // 1) weight fp32 -> bf16 conversions (embeddings cvt fused into GEMM)
  cvt_bf16<<<1728, 256, 0, stream>>>(qkv_w, wqkvB, 1769472 / 4);
  cvt_bf16<<<576, 256, 0, stream>>>(proj_w, wprojB, 589824 / 4);

  // 2) qkv = emb(fp32) @ qkv_w^T + qkv_b  (bf16 out; fused cvt, 2304 blocks)
  hipFuncSetAttribute(reinterpret_cast<const void*>(&gemm256f<1>),
                      hipFuncAttributeMaxDynamicSharedMemorySize, 131072);
  gemm256f<1><<<2304, 512, 131072, stream>>>(emb, wqkvB, qkv_b, qkvB,
                                             65536, 2304, 768);

  // 3) fused mask-unit attention (attn fp32 to d_out tail, X bf16 to ws)
  attn_kernel<<<3072, 256, 0, stream>>>(qkvB, out + 12582912, Xws);

  // 4) out = X @ proj_w^T + proj_b  (fp32 out)
  gemm_bt<0><<<dim3(128, 6), 256, 0, stream>>>(Xws, wprojB, proj_b, out,
                                               16384, 768, 768);
}

// Round 9
// 465.502 us; speedup vs baseline: 1.2707x; 1.2707x over previous
//
#include <hip/hip_runtime.h>
#include <hip/hip_bf16.h>

// HieraMaskUnitAttention on MI355X (gfx950).
// B=8 T=8192 D=768 H=12 HD=64 Q_STRIDE=4 WINDOW=64 -> nw=32, seq=256, q_len=64
//
// Pipeline (R9):
//   1) cvt_bf16: embeddings; cvt_w2: qkv_w + proj_w in ONE launch
//   2) gemm256p<bf16 out>: qkv = emb @ qkv_w^T + qkv_b  (R7-exact persistent)
//   3) attn_kernel (R7): Q max-pool, QK^T softmax (attn fp32 -> d_out), PV -> X ws
//   4) gemm256t<f32 out>: out = X @ proj_w^T + proj_b  (256^2 per-tile, 192 blocks)
//
// CLOSED BRANCHES (measured): A-cvt fusion into GEMM (R6 persistent: L3 blowout,
// FETCH 902MB; R8 per-tile: reg-stage load latency exposed, MfmaUtil 21%) —
// unfused cvt+gload_lds is strictly better. GEMM micro-schedule variants
// (sched_barrier pins, early-read pipeline, persistent vs per-tile) all pin at
// MfmaUtil ~37% / ~845 TF — the 2-blocks-waves-lockstep structure's plateau here.

typedef float  f32x4  __attribute__((ext_vector_type(4)));
typedef __bf16 bf16x8 __attribute__((ext_vector_type(8)));

__device__ __forceinline__ unsigned short f2bf(float f) {
  unsigned int u = __float_as_uint(f);
  u += 0x7fffu + ((u >> 16) & 1u);      // RNE
  return (unsigned short)(u >> 16);
}
__device__ __forceinline__ float bf2f(unsigned short b) {
  return __uint_as_float(((unsigned int)b) << 16);
}

#define GLOAD_LDS16(gptr, lptr) __builtin_amdgcn_global_load_lds( \
    (const __attribute__((address_space(1))) void*)(gptr),        \
    (__attribute__((address_space(3))) void*)(lptr), 16, 0, 0)

// ---------------------------------------------------------------- cvt fp32->bf16
__global__ void cvt_bf16(const float* __restrict__ src,
                         unsigned short* __restrict__ dst, int n4) {
  int i = blockIdx.x * blockDim.x + threadIdx.x;
  const int stride = gridDim.x * blockDim.x;
  for (; i < n4; i += stride) {
    const float4 v = ((const float4*)src)[i];
    ushort4 o;
    o.x = f2bf(v.x); o.y = f2bf(v.y); o.z = f2bf(v.z); o.w = f2bf(v.w);
    ((ushort4*)dst)[i] = o;
  }
}

// both weight tensors in one launch
__global__ void cvt_w2(const float* __restrict__ s1, unsigned short* __restrict__ d1,
                       int n1_4,
                       const float* __restrict__ s2, unsigned short* __restrict__ d2,
                       int n2_4) {
  int i = blockIdx.x * blockDim.x + threadIdx.x;
  const int stride = gridDim.x * blockDim.x;
  const int tot = n1_4 + n2_4;
  for (; i < tot; i += stride) {
    const float4 v = (i < n1_4) ? ((const float4*)s1)[i]
                                : ((const float4*)s2)[i - n1_4];
    ushort4 o;
    o.x = f2bf(v.x); o.y = f2bf(v.y); o.z = f2bf(v.z); o.w = f2bf(v.w);
    if (i < n1_4) ((ushort4*)d1)[i] = o;
    else          ((ushort4*)d2)[i - n1_4] = o;
  }
}

// ---------------------------------------------------------------- persistent 256x256 GEMM
// C = A @ B^T + bias. A: [M x K] bf16 K-fast, B: [N x K] bf16 K-fast. (R4/R7-exact)
// grid = M/256 blocks, 1/CU (128KB LDS). K-stream step s over n-tiles j.
// LDS regions: A(par,kh)=par*32768+kh*16384, B=+65536; par = s&1.
//   ph1 stage A-Kh1(s+1)   ph2 stage B-Kh1(s+1), vmcnt(8)
//   ph3 stage A-Kh0(s+2)   ph4 stage B-Kh0(s+2), vmcnt(8)
// Swizzle: byte p ^= ((p>>7)&3)<<4 pre-applied on global source, applied on reads.
template <int OUT_BF16>
__global__ __launch_bounds__(512, 2) void gemm256p(
    const unsigned short* __restrict__ A, const unsigned short* __restrict__ B,
    const float* __restrict__ bias, void* __restrict__ Cout,
    int M, int N, int K) {
  extern __shared__ char lds[];

  const int tid  = threadIdx.x;
  const int lane = tid & 63;
  const int wid  = tid >> 6;
  const int g16  = (lane >> 4) & 3;
  const int l15  = lane & 15;
  const int wm   = wid >> 2;
  const int wn   = wid & 3;

  const size_t bm = (size_t)blockIdx.x << 8;
  const int NT = K >> 6;
  const int NB = N >> 8;
  const int TT = NB * NT;

  const int srow = tid >> 2;
  const int csel = (((tid & 3) ^ ((tid >> 3) & 3)) << 3);
  const int ldst = wid * 1024;
  const unsigned short* pA0 = A + (bm + srow) * (size_t)K + csel;
  const unsigned short* pA1 = pA0 + (size_t)128 * K;
  const unsigned short* pB0 = B + (size_t)srow * K + csel;
  const unsigned short* pB1 = pB0 + (size_t)128 * K;

#define STAGE_A(koff, regbase)                                          \
  do {                                                                  \
    GLOAD_LDS16(pA0 + (koff), lds + (regbase) + ldst);                  \
    GLOAD_LDS16(pA1 + (koff), lds + (regbase) + 8192 + ldst);           \
  } while (0)
#define STAGE_B(boff, regbase)                                          \
  do {                                                                  \
    GLOAD_LDS16(pB0 + (boff), lds + (regbase) + ldst);                  \
    GLOAD_LDS16(pB1 + (boff), lds + (regbase) + 8192 + ldst);           \
  } while (0)

  const int s16  = ((g16 ^ ((l15 >> 1) & 3)) << 4);
  const int offA = (wm * 128 + l15) * 64 + s16;
  const int offB = (wn * 64 + l15) * 64 + s16;

  f32x4 acc[8][4];
  const f32x4 zero4 = {0.f, 0.f, 0.f, 0.f};
#pragma unroll
  for (int i = 0; i < 8; ++i)
#pragma unroll
    for (int j = 0; j < 4; ++j) acc[i][j] = zero4;

#define READ_A(par, kk, rh)                                              \
  { const char* rb = lds + (par) * 32768 + (kk) * 16384 + offA + (rh) * 4096; \
    af[0] = *(const bf16x8*)(rb);                                        \
    af[1] = *(const bf16x8*)(rb + 1024);                                 \
    af[2] = *(const bf16x8*)(rb + 2048);                                 \
    af[3] = *(const bf16x8*)(rb + 3072); }
#define READ_B(par, kk)                                                  \
  { const char* rb = lds + 65536 + (par) * 32768 + (kk) * 16384 + offB;  \
    bfv[0] = *(const bf16x8*)(rb);                                       \
    bfv[1] = *(const bf16x8*)(rb + 1024);                                \
    bfv[2] = *(const bf16x8*)(rb + 2048);                                \
    bfv[3] = *(const bf16x8*)(rb + 3072); }
#define MFMA16(rh)                                                       \
  _Pragma("unroll") for (int q = 0; q < 4; ++q)                          \
  _Pragma("unroll") for (int c = 0; c < 4; ++c)                          \
    acc[(rh) * 4 + q][c] = __builtin_amdgcn_mfma_f32_16x16x32_bf16(      \
        af[q], bfv[c], acc[(rh) * 4 + q][c], 0, 0, 0);
#define BAR() __builtin_amdgcn_s_barrier()
#define VMCNT8() asm volatile("s_waitcnt vmcnt(8)" ::: "memory")

  int    kk  = 0;
  int    bnC = 0;
  int    k1  = 64;
  int    k2  = 128;
  size_t rB1 = 0;
  size_t rB2 = 0;

  STAGE_A(0, 0);
  STAGE_B(0, 65536);
  STAGE_A(32, 16384);
  STAGE_B(32, 65536 + 16384);
  STAGE_A(64, 32768);
  STAGE_B(64, 65536 + 32768);
  VMCNT8();
  BAR();

  for (int s = 0; s < TT; ++s) {
    const int par  = s & 1;
    const int parn = par ^ 1;
    bf16x8 af[4], bfv[4];

    READ_A(par, 0, 0); READ_B(par, 0);
    STAGE_A(k1 + 32, parn * 32768 + 16384);
    BAR();
    __builtin_amdgcn_s_setprio(1); MFMA16(0); __builtin_amdgcn_s_setprio(0);
    BAR();

    READ_A(par, 0, 1);
    STAGE_B(rB1 + k1 + 32, 65536 + parn * 32768 + 16384);
    VMCNT8();
    BAR();
    __builtin_amdgcn_s_setprio(1); MFMA16(1); __builtin_amdgcn_s_setprio(0);
    BAR();

    READ_A(par, 1, 0); READ_B(par, 1);
    STAGE_A(k2, par * 32768);
    BAR();
    __builtin_amdgcn_s_setprio(1); MFMA16(0); __builtin_amdgcn_s_setprio(0);
    BAR();

    READ_A(par, 1, 1);
    STAGE_B(rB2 + k2, 65536 + par * 32768);
    VMCNT8();
    BAR();
    __builtin_amdgcn_s_setprio(1); MFMA16(1); __builtin_amdgcn_s_setprio(0);
    BAR();

    if (kk == NT - 1) {
#pragma unroll
      for (int ai = 0; ai < 8; ++ai) {
        const size_t row0 =
            bm + wm * 128 + (ai >> 2) * 64 + (ai & 3) * 16 + g16 * 4;
#pragma unroll
        for (int c = 0; c < 4; ++c) {
          const int col = bnC + wn * 64 + c * 16 + l15;
          const float bv = bias[col];
#pragma unroll
          for (int r = 0; r < 4; ++r) {
            const float v = acc[ai][c][r] + bv;
            const size_t idx = (row0 + r) * (size_t)N + col;
            if (OUT_BF16) ((unsigned short*)Cout)[idx] = f2bf(v);
            else          ((float*)Cout)[idx] = v;
          }
          acc[ai][c] = zero4;
        }
      }
      bnC += 256;
      kk = 0;
    } else {
      ++kk;
    }

    k1 = k2; rB1 = rB2;
    if (s + 3 < TT) {
      k2 += 64;
      if (k2 == K) { k2 = 0; rB2 += (size_t)256 * K; }
    }
  }
#undef STAGE_A
#undef STAGE_B
#undef READ_A
#undef READ_B
#undef MFMA16
#undef BAR
#undef VMCNT8
}

// ---------------------------------------------------------------- per-tile 256x256 GEMM
// C = A @ B^T + bias, both bf16 K-fast. Grid = (M/256)*(N/256), XCD-bijective
// swizzle, N-fast. (R2-measured structure; used for the proj GEMM.)
template <int OUT_BF16>
__global__ __launch_bounds__(512, 2) void gemm256t(
    const unsigned short* __restrict__ A, const unsigned short* __restrict__ B,
    const float* __restrict__ bias, void* __restrict__ Cout,
    int M, int N, int K) {
  extern __shared__ char lds[];

  const int tid  = threadIdx.x;
  const int lane = tid & 63;
  const int wid  = tid >> 6;
  const int g16  = (lane >> 4) & 3;
  const int l15  = lane & 15;
  const int wm   = wid >> 2;
  const int wn   = wid & 3;

  const int nbn = N >> 8;
  const int wg  = (blockIdx.x & 7) * ((int)gridDim.x >> 3) + (blockIdx.x >> 3);
  const size_t bm = (size_t)(wg / nbn) << 8;
  const size_t bn = (size_t)(wg % nbn) << 8;

  const int NT = K >> 6;

  const int srow = tid >> 2;
  const int csel = (((tid & 3) ^ ((tid >> 3) & 3)) << 3);
  const int ldst = wid * 1024;
  const unsigned short* pA0 = A + (bm + srow) * (size_t)K + csel;
  const unsigned short* pA1 = pA0 + (size_t)128 * K;
  const unsigned short* pB0 = B + (bn + srow) * (size_t)K + csel;
  const unsigned short* pB1 = pB0 + (size_t)128 * K;

#define STAGE(p0, p1, kcol, regbase)                                   \
  do {                                                                 \
    GLOAD_LDS16((p0) + (kcol), lds + (regbase) + ldst);                \
    GLOAD_LDS16((p1) + (kcol), lds + (regbase) + 8192 + ldst);         \
  } while (0)

  const int s16  = ((g16 ^ ((l15 >> 1) & 3)) << 4);
  const int offA = (wm * 128 + l15) * 64 + s16;
  const int offB = (wn * 64 + l15) * 64 + s16;

  f32x4 acc[8][4];
  const f32x4 zero4 = {0.f, 0.f, 0.f, 0.f};
#pragma unroll
  for (int i = 0; i < 8; ++i)
#pragma unroll
    for (int j = 0; j < 4; ++j) acc[i][j] = zero4;

#define READ_A(par, kk, rh)                                              \
  { const char* rb = lds + (par) * 32768 + (kk) * 16384 + offA + (rh) * 4096; \
    af[0] = *(const bf16x8*)(rb);                                        \
    af[1] = *(const bf16x8*)(rb + 1024);                                 \
    af[2] = *(const bf16x8*)(rb + 2048);                                 \
    af[3] = *(const bf16x8*)(rb + 3072); }
#define READ_B(par, kk)                                                  \
  { const char* rb = lds + 65536 + (par) * 32768 + (kk) * 16384 + offB;  \
    bfv[0] = *(const bf16x8*)(rb);                                       \
    bfv[1] = *(const bf16x8*)(rb + 1024);                                \
    bfv[2] = *(const bf16x8*)(rb + 2048);                                \
    bfv[3] = *(const bf16x8*)(rb + 3072); }
#define MFMA16(rh)                                                       \
  _Pragma("unroll") for (int q = 0; q < 4; ++q)                          \
  _Pragma("unroll") for (int c = 0; c < 4; ++c)                          \
    acc[(rh) * 4 + q][c] = __builtin_amdgcn_mfma_f32_16x16x32_bf16(      \
        af[q], bfv[c], acc[(rh) * 4 + q][c], 0, 0, 0);
#define BAR() __builtin_amdgcn_s_barrier()
#define VMCNT8() asm volatile("s_waitcnt vmcnt(8)" ::: "memory")

  STAGE(pA0, pA1, 0, 0);
  STAGE(pB0, pB1, 0, 65536);
  STAGE(pA0, pA1, 32, 16384);
  STAGE(pB0, pB1, 32, 65536 + 16384);
  {
    const int k1 = (NT > 1 ? 64 : 0);
    STAGE(pA0, pA1, k1, 32768);
    STAGE(pB0, pB1, k1, 65536 + 32768);
  }
  VMCNT8();
  BAR();

  for (int t = 0; t < NT; ++t) {
    const int par  = t & 1;
    const int parn = par ^ 1;
    const int kc1  = (t + 1 < NT ? t + 1 : NT - 1) * 64;
    const int kc2  = (t + 2 < NT ? t + 2 : NT - 1) * 64;
    bf16x8 af[4], bfv[4];

    READ_A(par, 0, 0); READ_B(par, 0);
    STAGE(pA0, pA1, kc1 + 32, parn * 32768 + 16384);
    BAR();
    __builtin_amdgcn_s_setprio(1); MFMA16(0); __builtin_amdgcn_s_setprio(0);
    BAR();

    READ_A(par, 0, 1);
    STAGE(pB0, pB1, kc1 + 32, 65536 + parn * 32768 + 16384);
    VMCNT8();
    BAR();
    __builtin_amdgcn_s_setprio(1); MFMA16(1); __builtin_amdgcn_s_setprio(0);
    BAR();

    READ_A(par, 1, 0); READ_B(par, 1);
    STAGE(pA0, pA1, kc2, par * 32768);
    BAR();
    __builtin_amdgcn_s_setprio(1); MFMA16(0); __builtin_amdgcn_s_setprio(0);
    BAR();

    READ_A(par, 1, 1);
    STAGE(pB0, pB1, kc2, 65536 + par * 32768);
    VMCNT8();
    BAR();
    __builtin_amdgcn_s_setprio(1); MFMA16(1); __builtin_amdgcn_s_setprio(0);
    BAR();
  }

#pragma unroll
  for (int ai = 0; ai < 8; ++ai) {
    const size_t row0 = bm + wm * 128 + (ai >> 2) * 64 + (ai & 3) * 16 + g16 * 4;
#pragma unroll
    for (int c = 0; c < 4; ++c) {
      const size_t col = bn + wn * 64 + c * 16 + l15;
      const float bv = bias[col];
#pragma unroll
      for (int r = 0; r < 4; ++r) {
        const float v = acc[ai][c][r] + bv;
        const size_t idx = (row0 + r) * N + col;
        if (OUT_BF16) ((unsigned short*)Cout)[idx] = f2bf(v);
        else          ((float*)Cout)[idx] = v;
      }
    }
  }
#undef STAGE
#undef READ_A
#undef READ_B
#undef MFMA16
#undef BAR
#undef VMCNT8
}

// ---------------------------------------------------------------- fused mask-unit attention
// One block (256 thr, 4 waves) per (b,h,w). Wave handles 16 q-rows. (R7-exact)
__global__ __launch_bounds__(256) void attn_kernel(
    const unsigned short* __restrict__ qkv,   // [65536 x 2304] bf16
    float* __restrict__ attn_out,             // [b,h,w,64,256] fp32
    unsigned short* __restrict__ Xws) {       // [16384 x 768] bf16
  __shared__ unsigned short smem[32768];
  char* KP = (char*)smem;             // 32KB K region / later P region
  char* VT = (char*)(smem + 16384);   // 32KB V transposed [d][s]

  const int tid  = threadIdx.x;
  const int lane = tid & 63;
  const int wid  = tid >> 6;
  const int g16  = lane >> 4;
  const int l15  = lane & 15;

  const int bid = blockIdx.x;         // ((b*12 + h)*32 + w)
  const int w = bid & 31;
  const int h = (bid >> 5) % 12;
  const int b = bid / 384;

  const int s0 = tid >> 3;            // 0..31
  const int part = tid & 7;

  // ---- stage K (swizzled rows, b128 writes) ----
#pragma unroll
  for (int p = 0; p < 8; ++p) {
    const int s = s0 + p * 32;
    const size_t gbase =
        ((size_t)b * 8192 + (size_t)s * 32 + w) * 2304 + h * 64 + part * 8;
    int4 kv = *(const int4*)(qkv + gbase + 768);
    *(int4*)(KP + ((s * 128 + part * 16) ^ ((s & 7) << 4))) = kv;
  }

  // ---- stage V transposed: 4 consecutive s per thread, packed b64 writes ----
#pragma unroll
  for (int p = 0; p < 2; ++p) {
    const int s = s0 * 4 + p * 128;   // 4-aligned
    const size_t gb0 =
        ((size_t)b * 8192 + (size_t)s * 32 + w) * 2304 + 1536 + h * 64 + part * 8;
    int4 x0 = *(const int4*)(qkv + gb0);
    int4 x1 = *(const int4*)(qkv + gb0 + 73728);    // +32*2304 (s+1)
    int4 x2 = *(const int4*)(qkv + gb0 + 147456);   // s+2
    int4 x3 = *(const int4*)(qkv + gb0 + 221184);   // s+3
    const unsigned int* u0 = (const unsigned int*)&x0;
    const unsigned int* u1 = (const unsigned int*)&x1;
    const unsigned int* u2 = (const unsigned int*)&x2;
    const unsigned int* u3 = (const unsigned int*)&x3;
#pragma unroll
    for (int k = 0; k < 4; ++k) {
      const unsigned int lo01 = (u0[k] & 0xffffu) | (u1[k] << 16);
      const unsigned int lo23 = (u2[k] & 0xffffu) | (u3[k] << 16);
      const unsigned int hi01 = (u0[k] >> 16) | (u1[k] & 0xffff0000u);
      const unsigned int hi23 = (u2[k] >> 16) | (u3[k] & 0xffff0000u);
      const int dlo = part * 8 + 2 * k;
      const int dhi = dlo + 1;
      uint2 vlo; vlo.x = lo01; vlo.y = lo23;
      uint2 vhi; vhi.x = hi01; vhi.y = hi23;
      *(uint2*)(VT + ((dlo * 512 + s * 2) ^ ((dlo & 7) << 4))) = vlo;
      *(uint2*)(VT + ((dhi * 512 + s * 2) ^ ((dhi & 7) << 4))) = vhi;
    }
  }

  // ---- gather Q with interleaved max-pool directly into A-fragments ----
  union BU { unsigned short u[8]; bf16x8 v; };
  BU aq0, aq1;
  {
    const int qrow = wid * 16 + l15;
    float q0[8], q1[8];
#pragma unroll
    for (int j = 0; j < 8; ++j) { q0[j] = -1e30f; q1[j] = -1e30f; }
#pragma unroll
    for (int g = 0; g < 4; ++g) {
      const size_t gbase =
          ((size_t)b * 8192 + (size_t)(g * 64 + qrow) * 32 + w) * 2304 +
          h * 64 + g16 * 8;
      int4 a = *(const int4*)(qkv + gbase);
      int4 c = *(const int4*)(qkv + gbase + 32);
      const unsigned short* pa = (const unsigned short*)&a;
      const unsigned short* pc = (const unsigned short*)&c;
#pragma unroll
      for (int j = 0; j < 8; ++j) {
        q0[j] = fmaxf(q0[j], bf2f(pa[j]));
        q1[j] = fmaxf(q1[j], bf2f(pc[j]));
      }
    }
#pragma unroll
    for (int j = 0; j < 8; ++j) {
      aq0.u[j] = (unsigned short)(__float_as_uint(q0[j]) >> 16);
      aq1.u[j] = (unsigned short)(__float_as_uint(q1[j]) >> 16);
    }
  }

  __syncthreads();

  // ---- S = Q K^T ----
  f32x4 sacc[16];
  const f32x4 zero4 = {0.f, 0.f, 0.f, 0.f};
#pragma unroll
  for (int t = 0; t < 16; ++t) sacc[t] = zero4;
#pragma unroll
  for (int t = 0; t < 16; ++t) {
    const int srow = t * 16 + l15;
    bf16x8 bk0 = *(const bf16x8*)(KP + ((srow * 128 + 0  + g16 * 16) ^ ((srow & 7) << 4)));
    bf16x8 bk1 = *(const bf16x8*)(KP + ((srow * 128 + 64 + g16 * 16) ^ ((srow & 7) << 4)));
    sacc[t] = __builtin_amdgcn_mfma_f32_16x16x32_bf16(aq0.v, bk0, sacc[t], 0, 0, 0);
    sacc[t] = __builtin_amdgcn_mfma_f32_16x16x32_bf16(aq1.v, bk1, sacc[t], 0, 0, 0);
  }

  // ---- softmax over 256 ----
  float inv_[4];
#pragma unroll
  for (int r = 0; r < 4; ++r) {
    float m = -1e30f;
#pragma unroll
    for (int t = 0; t < 16; ++t) { sacc[t][r] *= 0.125f; m = fmaxf(m, sacc[t][r]); }
#pragma unroll
    for (int off = 1; off < 16; off <<= 1) m = fmaxf(m, __shfl_xor(m, off, 64));
    float ssum = 0.f;
#pragma unroll
    for (int t = 0; t < 16; ++t) {
      float e = expf(sacc[t][r] - m);
      sacc[t][r] = e;
      ssum += e;
    }
#pragma unroll
    for (int off = 1; off < 16; off <<= 1) ssum += __shfl_xor(ssum, off, 64);
    inv_[r] = 1.f / ssum;
  }

  // ---- write attn (fp32), keep normalized P ----
  {
    float* ab = attn_out + ((size_t)bid * 64 + wid * 16) * 256;
#pragma unroll
    for (int t = 0; t < 16; ++t)
#pragma unroll
      for (int r = 0; r < 4; ++r) {
        const float p = sacc[t][r] * inv_[r];
        sacc[t][r] = p;
        ab[(size_t)(g16 * 4 + r) * 256 + t * 16 + l15] = p;
      }
  }

  __syncthreads();

  // ---- P (bf16) into per-wave LDS region, swizzled ----
  {
    char* PW = KP + wid * 8192;
#pragma unroll
    for (int t = 0; t < 16; ++t)
#pragma unroll
      for (int r = 0; r < 4; ++r) {
        const int row = g16 * 4 + r;
        *(unsigned short*)(PW + ((row * 512 + (t * 16 + l15) * 2) ^ ((row & 7) << 4))) =
            f2bf(sacc[t][r]);
      }
  }

  // ---- O = P V ----
  f32x4 oacc[4];
#pragma unroll
  for (int n = 0; n < 4; ++n) oacc[n] = zero4;
  {
    const char* PR = KP + wid * 8192;
#pragma unroll
    for (int kc = 0; kc < 8; ++kc) {
      bf16x8 pa = *(const bf16x8*)(PR + ((l15 * 512 + kc * 64 + g16 * 16) ^ ((l15 & 7) << 4)));
#pragma unroll
      for (int n = 0; n < 4; ++n) {
        const int d = n * 16 + l15;
        bf16x8 vv = *(const bf16x8*)(VT + ((d * 512 + kc * 64 + g16 * 16) ^ ((d & 7) << 4)));
        oacc[n] = __builtin_amdgcn_mfma_f32_16x16x32_bf16(pa, vv, oacc[n], 0, 0, 0);
      }
    }
  }

  // ---- write X for proj GEMM ----
#pragma unroll
  for (int n = 0; n < 4; ++n)
#pragma unroll
    for (int r = 0; r < 4; ++r) {
      const int qi = wid * 16 + g16 * 4 + r;
      Xws[((size_t)b * 2048 + qi * 32 + w) * 768 + h * 64 + n * 16 + l15] =
          f2bf(oacc[n][r]);
    }
}

// ---------------------------------------------------------------- launch
extern "C" void kernel_launch(void* const* d_in, const int* in_sizes, int n_in,
                              void* d_out, int out_size, void* d_ws, size_t ws_size,
                              hipStream_t stream) {
  const float* emb    = (const float*)d_in[0];
  const float* qkv_w  = (const float*)d_in[1];
  const float* qkv_b  = (const float*)d_in[2];
  const float* proj_w = (const float*)d_in[3];
  const float* proj_b = (const float*)d_in[4];
  float* out = (float*)d_out;

  char* ws = (char*)d_ws;
  unsigned short* embB   = (unsigned short*)(ws);
  unsigned short* wqkvB  = (unsigned short*)(ws + 100663296);
  unsigned short* wprojB = (unsigned short*)(ws + 104202240);
  unsigned short* qkvB   = (unsigned short*)(ws + 105381888);
  unsigned short* Xws    = (unsigned short*)(ws + 407371776);

  // 1) fp32 -> bf16 conversions (weights merged into one launch)
  cvt_bf16<<<4096, 256, 0, stream>>>(emb, embB, 50331648 / 4);
  cvt_w2<<<2048, 256, 0, stream>>>(qkv_w, wqkvB, 1769472 / 4,
                                   proj_w, wprojB, 589824 / 4);

  // 2) qkv = emb @ qkv_w^T + qkv_b  (bf16 out; persistent 256^2, 128KB dyn LDS)
  hipFuncSetAttribute(reinterpret_cast<const void*>(&gemm256p<1>),
                      hipFuncAttributeMaxDynamicSharedMemorySize, 131072);
  gemm256p<1><<<256, 512, 131072, stream>>>(embB, wqkvB, qkv_b, qkvB,
                                            65536, 2304, 768);

  // 3) fused mask-unit attention (attn fp32 to d_out tail, X bf16 to ws)
  attn_kernel<<<3072, 256, 0, stream>>>(qkvB, out + 12582912, Xws);

  // 4) out = X @ proj_w^T + proj_b  (fp32 out; 256^2 per-tile, 192 blocks)
  hipFuncSetAttribute(reinterpret_cast<const void*>(&gemm256t<0>),
                      hipFuncAttributeMaxDynamicSharedMemorySize, 131072);
  gemm256t<0><<<192, 512, 131072, stream>>>(Xws, wprojB, proj_b, out,
                                            16384, 768, 768);
}